// Round 14
// baseline (572.241 us; speedup 1.0000x reference)
//
#include <hip/hip_runtime.h>
#include <math.h>

#define NN 20000
#define NP 20480   // padded to 160*128 (full supertile groups)
#define EE 60000
#define BB 512
#define HC 1024
#define HH 4
#define CC 256

typedef _Float16 f16;
typedef f16 half8 __attribute__((ext_vector_type(8)));
typedef f16 f16x4 __attribute__((ext_vector_type(4)));
typedef float floatx4 __attribute__((ext_vector_type(4)));
typedef float floatx16 __attribute__((ext_vector_type(16)));

// A-fragment (and B-fragment) layout for barrier-free GEMM:
// Af[mblk][iter][kh][rg][kg*32+lr][e] = A[mblk*128 + rg*32 + lr][iter*32 + (kh*2+kg)*8 + e]
__device__ __forceinline__ size_t af_off(int n, int c) {
    int mblk = n >> 7, rr = n & 127;
    int iter = c >> 5, kc = c & 31;
    int kh = kc >> 4, kg = (kc >> 3) & 1, e = kc & 7;
    return ((((size_t)(mblk * 32 + iter) * 2 + kh) * 4 + (rr >> 5)) * 64 +
            (kg * 32 + (rr & 31))) * 8 + e;
}

// XCD-aware node remap v2: producer/consumer alignment.
// gemmep writes h_lin row-block mblk from blocks with bid%8 == (3+mblk)%8 (the
// supertile decomposition makes nblk vary in multiples of 8). Assign agg's node n
// (mblk = n>>7) to a block on the SAME XCD: class c = (3+mblk)%8; within class c
// the j-th node is n = (((c+5)&7) + 8*(j>>7))*128 + (j&127). Class sizes:
// 2432 (c=0..2), 2560 (c=3..6), 2464 (c=7, partial mblk 156) -> prefix
// P[c] = c*2432 + max(c-3,0)*128. Block bid (XCD bid%8) takes rank
// i = (bid%8)*2500 + bid/8 (~95% of ranks fall in class bid%8).
// af lines (4 consecutive nodes) stay within one 128-node group -> one XCD:
// write-combining locality of R6 preserved. If kernel-boundary invalidates L2
// clean lines, this remap is neutral; if they persist, own-row reads hit L2.
__device__ __forceinline__ int node_remap(int bid) {
    int i = (bid & 7) * 2500 + (bid >> 3);
    int c = 0;
    c += (i >= 2432); c += (i >= 4864); c += (i >= 7296); c += (i >= 9856);
    c += (i >= 12416); c += (i >= 14976); c += (i >= 17536);
    int ge = c - 3;
    int P = c * 2432 + ((ge > 0) ? ge * 128 : 0);
    int j = i - P;
    int mblk = ((c + 5) & 7) + ((j >> 7) << 3);
    return mblk * 128 + (j & 127);
}

// async global->LDS, 16B per lane (wave-uniform LDS base + lane*16 hardware semantics)
__device__ __forceinline__ void gload16(const f16* g, f16* l) {
    __builtin_amdgcn_global_load_lds((const __attribute__((address_space(1))) void*)g,
                                     (__attribute__((address_space(3))) void*)l, 16, 0, 0);
}

// ---------------- precompute kernels ----------------
// one launch zeroes ea_sums(4f) + counts(NN) + fill(NN) + out(BB*1024f)
__global__ void zero_kernel(float* __restrict__ ea_sums, int* __restrict__ counts,
                            int* __restrict__ fill, float* __restrict__ out) {
    int i = blockIdx.x * 256 + threadIdx.x;
    if (i < 4) ea_sums[i] = 0.f;
    for (int k = i; k < NN; k += 256 * 256) {
        counts[k] = 0;
        fill[k] = 0;
    }
    for (int k = i; k < BB * 1024 / 4; k += 256 * 256) {
        ((float4*)out)[k] = make_float4(0.f, 0.f, 0.f, 0.f);
    }
}

// merged ea_sum + hist [0,235) + bptr [235,314)
__global__ void ehist_kernel(const float* __restrict__ ea, const int* __restrict__ ei,
                             const int* __restrict__ batch, float* sums, int* counts,
                             int* bptr, int E_) {
    int bid = blockIdx.x;
    int t = threadIdx.x;
    if (bid < 235) {
        int e = bid * 256 + t;
        float s0 = 0.f, s1 = 0.f, s2 = 0.f;
        if (e < E_) {
            atomicAdd(&counts[ei[E_ + e]], 1);
            s0 = ea[e * 3 + 0];
            s1 = ea[e * 3 + 1];
            s2 = ea[e * 3 + 2];
        }
        for (int o = 32; o; o >>= 1) {
            s0 += __shfl_down(s0, o);
            s1 += __shfl_down(s1, o);
            s2 += __shfl_down(s2, o);
        }
        if ((t & 63) == 0) {
            atomicAdd(&sums[0], s0);
            atomicAdd(&sums[1], s1);
            atomicAdd(&sums[2], s2);
        }
    } else {
        int i = (bid - 235) * 256 + t;
        if (i >= NN) return;
        int b = batch[i];
        if (i == 0) {
            for (int bb = 0; bb <= b; bb++) bptr[bb] = 0;
        } else {
            int pb = batch[i - 1];
            if (pb != b) {
                for (int bb = pb + 1; bb <= b; bb++) bptr[bb] = i;
            }
        }
        if (i == NN - 1) {
            for (int bb = b + 1; bb <= BB; bb++) bptr[bb] = NN;
        }
    }
}

// scan1: per-block inclusive scan; psums[bid] = raw block total
__global__ void scan1_kernel(const int* __restrict__ counts, int* __restrict__ partial,
                             int* __restrict__ psums, int n) {
    __shared__ int sdata[256];
    int t = threadIdx.x;
    int i = blockIdx.x * 256 + t;
    int v = (i < n) ? counts[i] : 0;
    sdata[t] = v;
    __syncthreads();
#pragma unroll
    for (int off = 1; off < 256; off <<= 1) {
        int tmp = (t >= off) ? sdata[t - off] : 0;
        __syncthreads();
        sdata[t] += tmp;
        __syncthreads();
    }
    if (i < n) partial[i] = sdata[t];
    if (t == 255) psums[blockIdx.x] = sdata[255];
}

// scan3 (scan2 folded in): each block derives its own offset = sum of psums[0..bid)
// via one LDS reduction (nblk = 79 <= 256 threads).
__global__ void scan3_kernel(const int* __restrict__ partial, const int* __restrict__ psums,
                             int* __restrict__ indptr, int n, int nb) {
    __shared__ int soff[256];
    int t = threadIdx.x;
    int v = (t < nb && t < (int)blockIdx.x) ? psums[t] : 0;
    soff[t] = v;
    __syncthreads();
#pragma unroll
    for (int o = 128; o; o >>= 1) {
        if (t < o) soff[t] += soff[t + o];
        __syncthreads();
    }
    int off = soff[0];
    int i = blockIdx.x * 256 + t;
    if (i == 0) indptr[0] = 0;
    if (i < n) indptr[i + 1] = partial[i] + off;
}

__global__ void scatter_kernel(const int* __restrict__ ei, const int* __restrict__ indptr,
                               int* fill, int* sorted, int* sdst, int E_) {
    int e = blockIdx.x * 256 + threadIdx.x;
    if (e >= E_) return;
    int d = ei[E_ + e];
    int pos = indptr[d] + atomicAdd(&fill[d], 1);
    sorted[pos] = e;
    sdst[pos] = d;
}

// merged prep0: wbf [0,768) + wvec/w0vec/bnss [768,3859) + mmat [3859,3863)
__global__ void prep0_kernel(const float* __restrict__ w_rest, f16* __restrict__ Bf,
                             const float* __restrict__ att_src,
                             const float* __restrict__ att_dst,
                             const float* __restrict__ w0,
                             const float* __restrict__ bias012, const float* __restrict__ bn_g,
                             const float* __restrict__ bn_b, const float* __restrict__ bn_m,
                             const float* __restrict__ bn_v,
                             const float* __restrict__ w_edge,
                             const float* __restrict__ att_edge,
                             const float* __restrict__ ea_sums,
                             float* __restrict__ wsv, float* __restrict__ wdv,
                             float* __restrict__ w0s, float* __restrict__ w0d,
                             float2* __restrict__ bnss,
                             float* __restrict__ Mmat, float* __restrict__ ae_self,
                             float invE) {
    int bid = blockIdx.x;
    int t = threadIdx.x;
    if (bid < 768) {
        // wbf: w_rest[3][1024][1024] fp32 -> Bf fragment-major fp16
        __shared__ float tile[64][65];
        int bx = (bid & 15) * 64;        // n range
        int by = ((bid >> 4) & 15) * 64; // k range
        int l = bid >> 8;
        int tr = t >> 6, tc = t & 63;
#pragma unroll
        for (int i = 0; i < 16; i++) {
            int r = by + i * 4 + tr;
            tile[i * 4 + tr][tc] = w_rest[(size_t)l * 1048576 + (size_t)r * 1024 + bx + tc];
        }
        __syncthreads();
        f16* bl = Bf + (size_t)l * 1048576;
#pragma unroll
        for (int ii = 0; ii < 2; ii++) {
            int idx = ii * 256 + t;
            int nl = idx >> 3, kg8 = idx & 7;
            int n = bx + nl, k = by + kg8 * 8;
            half8 v;
#pragma unroll
            for (int e = 0; e < 8; e++) v[e] = (f16)tile[kg8 * 8 + e][nl];
            *(half8*)&bl[af_off(n, k)] = v;
        }
    } else if (bid < 3840) {
        int b = bid - 768;
        int l = b >> 10, k = b & 1023;
        int hp = t >> 6, lane = t & 63;
        int col = hp * 256 + lane * 4;
        const float* wrow = w_rest + (size_t)l * 1048576 + (size_t)k * 1024;
        float4 w4 = *(const float4*)&wrow[col];
        float4 a4 = *(const float4*)&att_src[(l + 1) * HC + col];
        float4 d4 = *(const float4*)&att_dst[(l + 1) * HC + col];
        float sp = w4.x * a4.x + w4.y * a4.y + w4.z * a4.z + w4.w * a4.w;
        float dp = w4.x * d4.x + w4.y * d4.y + w4.z * d4.z + w4.w * d4.w;
        for (int m = 1; m < 64; m <<= 1) {
            sp += __shfl_xor(sp, m);
            dp += __shfl_xor(dp, m);
        }
        if (lane == 0) {
            wsv[((size_t)l * 1024 + k) * 4 + hp] = sp;
            wdv[((size_t)l * 1024 + k) * 4 + hp] = dp;
        }
    } else if (bid < 3847) {
        int f = bid - 3840;
        int hp = t >> 6, lane = t & 63;
        int col = hp * 256 + lane * 4;
        float4 w4 = *(const float4*)&w0[f * HC + col];
        float4 a4 = *(const float4*)&att_src[col];
        float4 d4 = *(const float4*)&att_dst[col];
        float sp = w4.x * a4.x + w4.y * a4.y + w4.z * a4.z + w4.w * a4.w;
        float dp = w4.x * d4.x + w4.y * d4.y + w4.z * d4.z + w4.w * d4.w;
        for (int m = 1; m < 64; m <<= 1) {
            sp += __shfl_xor(sp, m);
            dp += __shfl_xor(dp, m);
        }
        if (lane == 0) {
            w0s[f * 4 + hp] = sp;
            w0d[f * 4 + hp] = dp;
        }
    } else if (bid < 3859) {
        int i = (bid - 3847) * 256 + t;
        if (i < 3 * HC) {
            float s = bn_g[i] * rsqrtf(bn_v[i] + 1e-5f);
            float2 o;
            o.x = s;
            o.y = (bias012[i] - bn_m[i]) * s + bn_b[i];
            bnss[i] = o;
        }
    } else {
        // mmat: Mmat[l][d][h]; ae_self[l][h]
        __shared__ float red[256];
        __shared__ float Ms[12];
        int l = bid - 3859;
        for (int dh = 0; dh < 12; dh++) {
            int d = dh >> 2, hh = dh & 3;
            float v = w_edge[l * 3072 + d * HC + hh * CC + t] *
                      att_edge[l * HC + hh * CC + t];
            red[t] = v;
            __syncthreads();
            for (int o = 128; o; o >>= 1) {
                if (t < o) red[t] += red[t + o];
                __syncthreads();
            }
            if (t == 0) {
                Ms[dh] = red[0];
                Mmat[l * 12 + dh] = red[0];
            }
            __syncthreads();
        }
        if (t < 4) {
            float v = 0.f;
            for (int d = 0; d < 3; d++) v += ea_sums[d] * invE * Ms[d * 4 + t];
            ae_self[l * 4 + t] = v;
        }
    }
}

// merged prep2: pack [0,235) + alpha0/xpad [235,314)
__global__ void prep2_kernel(const int* __restrict__ ei, const int* __restrict__ sorted,
                             const float* __restrict__ ea, const float* __restrict__ Mmat,
                             int* __restrict__ ssrc, float* __restrict__ aeh_pk,
                             const float* __restrict__ x, const float* __restrict__ w0s,
                             const float* __restrict__ w0d, float* __restrict__ asrc,
                             float* __restrict__ adst, float* __restrict__ xpad) {
    int bid = blockIdx.x;
    int t = threadIdx.x;
    if (bid < 235) {
        int idx = bid * 256 + t;
        if (idx >= EE) return;
        int eid = sorted[idx];
        ssrc[idx] = ei[eid];
        float a0 = ea[eid * 3 + 0], a1 = ea[eid * 3 + 1], a2 = ea[eid * 3 + 2];
#pragma unroll
        for (int l = 0; l < 4; l++) {
#pragma unroll
            for (int h = 0; h < 4; h++) {
                aeh_pk[(size_t)idx * 16 + l * 4 + h] =
                    a0 * Mmat[l * 12 + h] + a1 * Mmat[l * 12 + 4 + h] +
                    a2 * Mmat[l * 12 + 8 + h];
            }
        }
    } else {
        int n = (bid - 235) * 256 + t;
        if (n >= NN) return;
        float xr[7];
#pragma unroll
        for (int f = 0; f < 7; f++) xr[f] = x[n * 7 + f];
        float4 p0, p1;
        p0.x = xr[0]; p0.y = xr[1]; p0.z = xr[2]; p0.w = xr[3];
        p1.x = xr[4]; p1.y = xr[5]; p1.z = xr[6]; p1.w = 0.f;
        *(float4*)&xpad[(size_t)n * 8] = p0;
        *(float4*)&xpad[(size_t)n * 8 + 4] = p1;
#pragma unroll
        for (int hp = 0; hp < 4; hp++) {
            float s = 0.f, d = 0.f;
#pragma unroll
            for (int f = 0; f < 7; f++) {
                s += xr[f] * w0s[f * 4 + hp];
                d += xr[f] * w0d[f * 4 + hp];
            }
            asrc[n * 4 + hp] = s;
            adst[n * 4 + hp] = d;
        }
    }
}

// per-layer edge-parallel softmax numerator (standalone for layer 0)
__global__ void edgep_kernel(const int* __restrict__ ssrc, const int* __restrict__ sdst,
                             const float* __restrict__ aeh_pk, const float* __restrict__ asrc,
                             const float* __restrict__ adst, float* __restrict__ pe,
                             int layer) {
    int i = blockIdx.x * 256 + threadIdx.x;
    if (i >= EE) return;
    int src = ssrc[i];
    int dst = sdst[i];
    float4 a = *(const float4*)&asrc[(size_t)src * 4];
    float4 d = *(const float4*)&adst[(size_t)dst * 4];
    float4 m = *(const float4*)&aeh_pk[(size_t)i * 16 + layer * 4];
    float r[4] = {a.x + d.x + m.x, a.y + d.y + m.y, a.z + d.z + m.z, a.w + d.w + m.w};
    float4 o;
#pragma unroll
    for (int k = 0; k < 4; k++) {
        float v = (r[k] > 0.f) ? r[k] : 0.2f * r[k];
        (&o.x)[k] = __expf(v);
    }
    *(float4*)&pe[(size_t)i * 4] = o;
}

// ---------------- layer 0 (commuted) ----------------
__global__ void agg0x_kernel(const float* __restrict__ xpad, const float* __restrict__ asrc,
                             const float* __restrict__ adst, const float* __restrict__ ae_self,
                             const int* __restrict__ ssrc, const float* __restrict__ pe,
                             const int* __restrict__ indptr, float* __restrict__ xagg) {
    int n = blockIdx.x * 256 + threadIdx.x;
    if (n >= NN) return;
    float4 as4 = *(const float4*)&asrc[(size_t)n * 4];
    float4 ad4 = *(const float4*)&adst[(size_t)n * 4];
    float adl[4] = {ad4.x, ad4.y, ad4.z, ad4.w};
    float asl[4] = {as4.x, as4.y, as4.z, as4.w};
    float4 x0 = *(const float4*)&xpad[(size_t)n * 8];
    float4 x1 = *(const float4*)&xpad[(size_t)n * 8 + 4];
    float xr[7] = {x0.x, x0.y, x0.z, x0.w, x1.x, x1.y, x1.z};
    float denom[4];
    float xa[4][7];
#pragma unroll
    for (int h = 0; h < 4; h++) {
        float r = asl[h] + adl[h] + ae_self[h];
        r = (r > 0.f) ? r : 0.2f * r;
        float p = __expf(r);
        denom[h] = p;
#pragma unroll
        for (int f = 0; f < 7; f++) xa[h][f] = p * xr[f];
    }
    int s = indptr[n], e = indptr[n + 1];
    for (int idx = s; idx < e; idx++) {
        int src = ssrc[idx];
        float4 pv = *(const float4*)&pe[(size_t)idx * 4];
        float pl[4] = {pv.x, pv.y, pv.z, pv.w};
        float4 s0 = *(const float4*)&xpad[(size_t)src * 8];
        float4 s1 = *(const float4*)&xpad[(size_t)src * 8 + 4];
        float xs[7] = {s0.x, s0.y, s0.z, s0.w, s1.x, s1.y, s1.z};
#pragma unroll
        for (int h = 0; h < 4; h++) {
            denom[h] += pl[h];
#pragma unroll
            for (int f = 0; f < 7; f++) xa[h][f] += pl[h] * xs[f];
        }
    }
#pragma unroll
    for (int h = 0; h < 4; h++) {
        float inv = 1.0f / (denom[h] + 1e-16f);
#pragma unroll
        for (int f = 0; f < 7; f++) xagg[(size_t)n * 28 + h * 7 + f] = xa[h][f] * inv;
    }
}

// h_act = relu(BN(xagg @ w0)) in Af layout + next-layer alpha epilogue.
// 32 nodes (one lr-group: fixed mblk,rg) per 256-thread block.
__global__ void gemm7f_kernel(const float* __restrict__ xagg, const float* __restrict__ w0,
                              const float2* __restrict__ bnss, const float* __restrict__ wsv,
                              const float* __restrict__ wdv, f16* __restrict__ outAf,
                              float* __restrict__ asrc_n, float* __restrict__ adst_n) {
    __shared__ float xs[32][29];
    __shared__ float red[4][32][8];
    int bid = blockIdx.x;
    int t = threadIdx.x;
    int n0 = bid * 32;
    int mblk = bid >> 2, rg = bid & 3;
    for (int i = t; i < 896; i += 256) xs[i / 28][i % 28] = xagg[(size_t)n0 * 28 + i];
    __syncthreads();
    int w = t >> 6, lane = t & 63;
    int lr = lane & 31, kg = lane >> 5;
    float x7[7];
#pragma unroll
    for (int f = 0; f < 7; f++) x7[f] = xs[lr][w * 7 + f];
    float sp[4] = {0.f, 0.f, 0.f, 0.f}, dp[4] = {0.f, 0.f, 0.f, 0.f};
#pragma unroll
    for (int p = 0; p < 16; p++) {
        int iter = w * 8 + (p >> 1);
        int kh = p & 1;
        int c0 = iter * 32 + (kh * 2 + kg) * 8;
        float dot[8];
#pragma unroll
        for (int e = 0; e < 8; e++) dot[e] = 0.f;
#pragma unroll
        for (int f = 0; f < 7; f++) {
            float4 wa = *(const float4*)&w0[f * HC + c0];
            float4 wb = *(const float4*)&w0[f * HC + c0 + 4];
            dot[0] += x7[f] * wa.x; dot[1] += x7[f] * wa.y;
            dot[2] += x7[f] * wa.z; dot[3] += x7[f] * wa.w;
            dot[4] += x7[f] * wb.x; dot[5] += x7[f] * wb.y;
            dot[6] += x7[f] * wb.z; dot[7] += x7[f] * wb.w;
        }
        half8 o;
#pragma unroll
        for (int e = 0; e < 8; e++) {
            int j = c0 + e;
            float2 ss = bnss[j];
            float val = fmaxf(fmaf(dot[e], ss.x, ss.y), 0.f);
            o[e] = (f16)val;
            float4 w4s = *(const float4*)&wsv[(size_t)j * 4];
            float4 w4d = *(const float4*)&wdv[(size_t)j * 4];
            sp[0] += val * w4s.x; sp[1] += val * w4s.y;
            sp[2] += val * w4s.z; sp[3] += val * w4s.w;
            dp[0] += val * w4d.x; dp[1] += val * w4d.y;
            dp[2] += val * w4d.z; dp[3] += val * w4d.w;
        }
        size_t off = ((((size_t)(mblk * 32 + iter) * 2 + kh) * 4 + rg) * 64 + lane) * 8;
        *(half8*)&outAf[off] = o;
    }
#pragma unroll
    for (int q = 0; q < 4; q++) {
        sp[q] += __shfl_xor(sp[q], 32);
        dp[q] += __shfl_xor(dp[q], 32);
    }
    if (kg == 0) {
#pragma unroll
        for (int q = 0; q < 4; q++) {
            red[w][lr][q] = sp[q];
            red[w][lr][4 + q] = dp[q];
        }
    }
    __syncthreads();
    {
        int lr2 = t >> 3, q = t & 7;
        float v = red[0][lr2][q] + red[1][lr2][q] + red[2][lr2][q] + red[3][lr2][q];
        if (q < 4) asrc_n[(size_t)(n0 + lr2) * 4 + q] = v;
        else adst_n[(size_t)(n0 + lr2) * 4 + (q - 4)] = v;
    }
}

// ---------------- GEMM (layers 1-3) + fused edgep ----------------
// Blocks [0,235): edgep. Blocks [235,1515): LDS GEMM, 3-buffer rotation (BK=32,
// 3 x 16KB = 48KB LDS -> 3 blocks/CU): ONE barrier per K-tile; counted vmcnt(4)
// keeps the next tile's loads in flight across the barrier (T4); stage before
// MFMA cluster (T3); setprio around MFMA (T5); sched_barrier fences (rule #18).
#define EPB 235
__global__ __launch_bounds__(256) void gemmep_kernel(
    const f16* __restrict__ Af, const f16* __restrict__ Bf, f16* __restrict__ C16,
    const int* __restrict__ ssrc, const int* __restrict__ sdst,
    const float* __restrict__ aeh_pk, const float* __restrict__ asrc,
    const float* __restrict__ adst, float* __restrict__ pe, int layer) {
    __shared__ __align__(16) f16 lds[24576];  // 3 bufs x (4096 A + 4096 B) f16
    int t = threadIdx.x;
    int bid = blockIdx.x;
    if (bid < EPB) {
        int i = bid * 256 + t;
        if (i >= EE) return;
        int src = ssrc[i];
        int dst = sdst[i];
        float4 a = *(const float4*)&asrc[(size_t)src * 4];
        float4 d = *(const float4*)&adst[(size_t)dst * 4];
        float4 m = *(const float4*)&aeh_pk[(size_t)i * 16 + layer * 4];
        float r[4] = {a.x + d.x + m.x, a.y + d.y + m.y, a.z + d.z + m.z, a.w + d.w + m.w};
        float4 o;
#pragma unroll
        for (int k = 0; k < 4; k++) {
            float v = (r[k] > 0.f) ? r[k] : 0.2f * r[k];
            (&o.x)[k] = __expf(v);
        }
        *(float4*)&pe[(size_t)i * 4] = o;
        return;
    }
    int gid = bid - EPB;
    int w = t >> 6, lane = t & 63;
    int g = gid >> 6, rblk = gid & 63;
    int nblk = rblk >> 3;
    int mblk = g * 8 + (rblk & 7);
    int rg0 = (w >> 1) * 2;
    int cg0 = (w & 1) * 2;

    floatx16 acc[2][2];
#pragma unroll
    for (int i = 0; i < 2; i++)
#pragma unroll
        for (int j = 0; j < 2; j++) acc[i][j] = (floatx16)(0.f);

    const f16* ga0 = Af + (size_t)mblk * 131072 + w * 1024 + lane * 8;
    const f16* gb0 = Bf + (size_t)nblk * 131072 + w * 1024 + lane * 8;

    // stage iter 'it' into buffer b: 4 async 1KB-per-wave issues
    auto STAGE = [&](int it, int b) {
        const f16* ga = ga0 + (size_t)it * 4096;
        const f16* gb = gb0 + (size_t)it * 4096;
        f16* base = &lds[b * 8192 + w * 1024 + lane * 8];
        gload16(ga, base);
        gload16(ga + 512, base + 512);
        gload16(gb, base + 4096);
        gload16(gb + 512, base + 4608);
    };
    auto COMPUTE = [&](int b) {
        half8 afr[2][2], bfr[2][2];
#pragma unroll
        for (int kh = 0; kh < 2; kh++) {
#pragma unroll
            for (int i = 0; i < 2; i++) {
                afr[kh][i] = *(const half8*)&lds[b * 8192 + kh * 2048 + (rg0 + i) * 512 +
                                                 lane * 8];
                bfr[kh][i] = *(const half8*)&lds[b * 8192 + 4096 + kh * 2048 +
                                                 (cg0 + i) * 512 + lane * 8];
            }
        }
#pragma unroll
        for (int kh = 0; kh < 2; kh++)
#pragma unroll
            for (int i = 0; i < 2; i++)
#pragma unroll
                for (int j = 0; j < 2; j++)
                    acc[i][j] = __builtin_amdgcn_mfma_f32_32x32x16_f16(bfr[kh][j], afr[kh][i],
                                                                       acc[i][j], 0, 0, 0);
    };

    STAGE(0, 0);
    STAGE(1, 1);
    int cb = 0, sb = 2;
#pragma unroll 1
    for (int k = 0; k < 31; k++) {
        asm volatile("s_waitcnt vmcnt(4)" ::: "memory");
        __builtin_amdgcn_s_barrier();
        __builtin_amdgcn_sched_barrier(0);
        if (k < 30) {
            STAGE(k + 2, sb);
            sb = (sb == 2) ? 0 : sb + 1;
        }
        __builtin_amdgcn_s_setprio(1);
        COMPUTE(cb);
        __builtin_amdgcn_s_setprio(0);
        cb = (cb == 2) ? 0 : cb + 1;
    }
    asm volatile("s_waitcnt vmcnt(0)" ::: "memory");
    __builtin_amdgcn_s_barrier();
    __builtin_amdgcn_sched_barrier(0);
    __builtin_amdgcn_s_setprio(1);
    COMPUTE(cb);
    __builtin_amdgcn_s_setprio(0);

    int fr32 = lane & 31, kg = lane >> 5;
#pragma unroll
    for (int i = 0; i < 2; i++) {
        int row = mblk * 128 + rg0 * 32 + i * 32 + fr32;
#pragma unroll
        for (int j = 0; j < 2; j++) {
#pragma unroll
            for (int gq = 0; gq < 4; gq++) {
                f16x4 o;
#pragma unroll
                for (int r = 0; r < 4; r++) o[r] = (f16)acc[i][j][gq * 4 + r];
                *(f16x4*)&C16[(size_t)row * HC + nblk * 128 + cg0 * 32 + j * 32 + gq * 8 +
                              kg * 4] = o;
            }
        }
    }
}

// ---------------- fused attention + aggregation (block per node, chunk-4) ----------
// R8-proven inner loop (unconditional gathers + self-row fallback).
__global__ void agg_kernel(const f16* __restrict__ h16, const float* __restrict__ asrc,
                           const float* __restrict__ adst, const float* __restrict__ ae_self,
                           const int* __restrict__ ssrc, const float* __restrict__ pe,
                           const int* __restrict__ indptr, const float2* __restrict__ bnss,
                           const float* __restrict__ wsv, const float* __restrict__ wdv,
                           const float* __restrict__ bias3, const float* __restrict__ gw,
                           const float* __restrict__ gb, f16* __restrict__ out16,
                           float* __restrict__ asrc_n, float* __restrict__ adst_n,
                           float* __restrict__ out3, float* __restrict__ gate,
                           int layer, int concat) {
    __shared__ float buf[1024];
    __shared__ float red[32];
    int n = node_remap(blockIdx.x);
    int t = threadIdx.x;
    int h = t >> 6, lane = t & 63;
    int c4 = t * 4;

    float r = asrc[n * 4 + h] + adst[n * 4 + h] + ae_self[layer * 4 + h];
    r = (r > 0.f) ? r : 0.2f * r;
    float p = __expf(r);
    float denom = p;
    float ax, ay, az, aw;
    {
        f16x4 v = *(const f16x4*)&h16[(size_t)n * HC + c4];
        ax = p * (float)v[0]; ay = p * (float)v[1];
        az = p * (float)v[2]; aw = p * (float)v[3];
    }
    int s = indptr[n], epos = indptr[n + 1];
    for (int base = s; base < epos; base += 4) {
        int rem = epos - base;
        int src[4];
        float pv[4];
#pragma unroll
        for (int j = 0; j < 4; j++) {
            if (j < rem) {
                src[j] = ssrc[base + j];
                pv[j] = pe[(size_t)(base + j) * 4 + h];
            } else {
                src[j] = n;
                pv[j] = 0.f;
            }
        }
        f16x4 u[4];
#pragma unroll
        for (int j = 0; j < 4; j++) u[j] = *(const f16x4*)&h16[(size_t)src[j] * HC + c4];
#pragma unroll
        for (int j = 0; j < 4; j++) {
            denom += pv[j];
            ax += pv[j] * (float)u[j][0];
            ay += pv[j] * (float)u[j][1];
            az += pv[j] * (float)u[j][2];
            aw += pv[j] * (float)u[j][3];
        }
    }
    float inv = 1.0f / (denom + 1e-16f);
    ax *= inv; ay *= inv; az *= inv; aw *= inv;

    if (concat) {
        float vals[4] = {ax, ay, az, aw};
        f16x4 o;
        float sp[4] = {0.f, 0.f, 0.f, 0.f}, dp[4] = {0.f, 0.f, 0.f, 0.f};
#pragma unroll
        for (int k = 0; k < 4; k++) {
            int j = c4 + k;
            float2 ss = bnss[j];
            float val = fmaxf(fmaf(vals[k], ss.x, ss.y), 0.f);
            o[k] = (f16)val;
            float4 w4s = *(const float4*)&wsv[(size_t)j * 4];
            float4 w4d = *(const float4*)&wdv[(size_t)j * 4];
            sp[0] += val * w4s.x; sp[1] += val * w4s.y;
            sp[2] += val * w4s.z; sp[3] += val * w4s.w;
            dp[0] += val * w4d.x; dp[1] += val * w4d.y;
            dp[2] += val * w4d.z; dp[3] += val * w4d.w;
        }
        *(f16x4*)&out16[af_off(n, c4)] = o;
#pragma unroll
        for (int m = 1; m < 64; m <<= 1) {
#pragma unroll
            for (int j = 0; j < 4; j++) {
                sp[j] += __shfl_xor(sp[j], m);
                dp[j] += __shfl_xor(dp[j], m);
            }
        }
        if (lane == 0) {
#pragma unroll
            for (int j = 0; j < 4; j++) {
                red[h * 8 + j] = sp[j];
                red[h * 8 + 4 + j] = dp[j];
            }
        }
        __syncthreads();
        if (t < 8) {
            float v = red[t] + red[8 + t] + red[16 + t] + red[24 + t];
            if (t < 4) asrc_n[n * 4 + t] = v;
            else adst_n[n * 4 + (t - 4)] = v;
        }
    } else {
        buf[c4 + 0] = ax;
        buf[c4 + 1] = ay;
        buf[c4 + 2] = az;
        buf[c4 + 3] = aw;
        __syncthreads();
        if (t < 64) {
            float gpart = 0.f;
            float4 v4;
#pragma unroll
            for (int k = 0; k < 4; k++) {
                int c = t * 4 + k;
                float v2 = 0.25f * (buf[c] + buf[256 + c] + buf[512 + c] + buf[768 + c]) +
                           bias3[c];
                (&v4.x)[k] = v2;
                gpart += v2 * gw[c];
            }
            *(float4*)&out3[(size_t)n * CC + t * 4] = v4;
            for (int o = 32; o; o >>= 1) gpart += __shfl_down(gpart, o);
            if (t == 0) gate[n] = gpart + gb[0];
        }
    }
}

// ---------------- readout ----------------
__global__ void graphagg_kernel(const float* __restrict__ gate, const float* __restrict__ h3,
                                const int* __restrict__ bptr, float* __restrict__ graph) {
    __shared__ float red[256];
    __shared__ float wn[256];
    int b = blockIdx.x, t = threadIdx.x;
    int s = bptr[b], epos = bptr[b + 1];
    float m = -3.4e38f;
    for (int n = s + t; n < epos; n += 256) m = fmaxf(m, gate[n]);
    red[t] = m;
    __syncthreads();
    for (int o = 128; o; o >>= 1) {
        if (t < o) red[t] = fmaxf(red[t], red[t + o]);
        __syncthreads();
    }
    float mval = red[0];
    __syncthreads();
    float sum = 0.f;
    for (int n = s + t; n < epos; n += 256) sum += __expf(gate[n] - mval);
    red[t] = sum;
    __syncthreads();
    for (int o = 128; o; o >>= 1) {
        if (t < o) red[t] += red[t + o];
        __syncthreads();
    }
    float ssum = red[0];
    __syncthreads();
    float acc = 0.f;
    for (int base = s; base < epos; base += 256) {
        int n = base + t;
        wn[t] = (n < epos) ? __expf(gate[n] - mval) : 0.f;
        __syncthreads();
        int cnt = min(256, epos - base);
        for (int j = 0; j < cnt; j++) acc += wn[j] * h3[(size_t)(base + j) * CC + t];
        __syncthreads();
    }
    graph[b * CC + t] = acc / (ssum + 1e-16f);
}

// 4-way c-split x 64 graph-groups = 256 blocks; out pre-zeroed, partials atomicAdd
// (disjoint cache lines, no contention). Chunk 0 adds the bias.
__global__ void proj_kernel(const float* __restrict__ graph, const float* __restrict__ pw,
                            const float* __restrict__ pb, float* __restrict__ out) {
    __shared__ float g[8][64];
    int bid = blockIdx.x;
    int grp = bid >> 2, cch = bid & 3;
    int t = threadIdx.x;
    int c0 = cch * 64;
    for (int i = t; i < 512; i += 256) {
        int r = i >> 6, c = i & 63;
        g[r][c] = graph[(size_t)(grp * 8 + r) * 256 + c0 + c];
    }
    __syncthreads();
    float acc[8][4];
#pragma unroll
    for (int r = 0; r < 8; r++)
#pragma unroll
        for (int q = 0; q < 4; q++) acc[r][q] = 0.f;
    if (cch == 0) {
#pragma unroll
        for (int q = 0; q < 4; q++) {
            float b = pb[t + q * 256];
#pragma unroll
            for (int r = 0; r < 8; r++) acc[r][q] += b;
        }
    }
    for (int c = 0; c < 64; c++) {
        float w[4];
#pragma unroll
        for (int q = 0; q < 4; q++) w[q] = pw[(size_t)(c0 + c) * 1024 + t + q * 256];
#pragma unroll
        for (int r = 0; r < 8; r++) {
            float gv = g[r][c];
#pragma unroll
            for (int q = 0; q < 4; q++) acc[r][q] += gv * w[q];
        }
    }
#pragma unroll
    for (int r = 0; r < 8; r++)
#pragma unroll
        for (int q = 0; q < 4; q++)
            atomicAdd(&out[(size_t)(grp * 8 + r) * 1024 + t + q * 256], acc[r][q]);
}

// ---------------- host ----------------
extern "C" void kernel_launch(void* const* d_in, const int* in_sizes, int n_in,
                              void* d_out, int out_size, void* d_ws, size_t ws_size,
                              hipStream_t stream) {
    const float* x = (const float*)d_in[0];
    const int* ei = (const int*)d_in[1];
    const float* ea = (const float*)d_in[2];
    const int* batch = (const int*)d_in[3];
    const float* w0 = (const float*)d_in[4];
    const float* w_rest = (const float*)d_in[5];
    const float* w_edge = (const float*)d_in[6];
    const float* att_src = (const float*)d_in[7];
    const float* att_dst = (const float*)d_in[8];
    const float* att_edge = (const float*)d_in[9];
    const float* bias012 = (const float*)d_in[10];
    const float* bias3 = (const float*)d_in[11];
    const float* bn_g = (const float*)d_in[12];
    const float* bn_b = (const float*)d_in[13];
    const float* bn_m = (const float*)d_in[14];
    const float* bn_v = (const float*)d_in[15];
    const float* gate_w = (const float*)d_in[16];
    const float* gate_b = (const float*)d_in[17];
    const float* proj_w = (const float*)d_in[18];
    const float* proj_b = (const float*)d_in[19];
    float* out = (float*)d_out;

    float* ws = (float*)d_ws;
    size_t off = 0;
    f16* h_lin = (f16*)(ws + off); off += (size_t)NP * HC / 2;   // GEMM output (row-major)
    f16* h_af = (f16*)(ws + off); off += (size_t)NP * HC / 2;    // GEMM input (Af layout)
    float* h3 = ws + off; off += (size_t)NN * CC;
    f16* Bf = (f16*)(ws + off); off += (size_t)3 * HC * HC / 2;  // B fragment-major
    float* xpad = ws + off; off += (size_t)NN * 8;
    float* asrcA = ws + off; off += (size_t)NN * 4;
    float* adstA = ws + off; off += (size_t)NN * 4;
    float* asrcB = ws + off; off += (size_t)NN * 4;
    float* adstB = ws + off; off += (size_t)NN * 4;
    float* wsv = ws + off; off += (size_t)3 * HC * 4;
    float* wdv = ws + off; off += (size_t)3 * HC * 4;
    float* w0s = ws + off; off += 28;
    float* w0d = ws + off; off += 28;
    float2* bnss = (float2*)(ws + off); off += (size_t)3 * HC * 2;
    float* aeh_pk = ws + off; off += (size_t)EE * 16;
    float* pbuf = ws + off; off += (size_t)EE * 4;
    float* xagg = ws + off; off += (size_t)NN * 28;
    float* gate = ws + off; off += (size_t)NN;
    float* graph = ws + off; off += (size_t)BB * CC;
    float* ea_sums = ws + off; off += 4;
    float* Mmat = ws + off; off += 48;
    float* ae_self = ws + off; off += 16;
    int* counts = (int*)(ws + off); off += NN;
    int* partial = (int*)(ws + off); off += NN;
    int* psums = (int*)(ws + off); off += 128;
    int* indptr = (int*)(ws + off); off += NN + 1;
    int* fill = (int*)(ws + off); off += NN;
    int* sorted = (int*)(ws + off); off += EE;
    int* ssrc = (int*)(ws + off); off += EE;
    int* sdst = (int*)(ws + off); off += EE;
    int* bptr = (int*)(ws + off); off += BB + 1;

    int nblk = (NN + 255) / 256;  // 79
    zero_kernel<<<256, 256, 0, stream>>>(ea_sums, counts, fill, out);
    ehist_kernel<<<235 + nblk, 256, 0, stream>>>(ea, ei, batch, ea_sums, counts, bptr, EE);
    scan1_kernel<<<nblk, 256, 0, stream>>>(counts, partial, psums, NN);
    scan3_kernel<<<nblk, 256, 0, stream>>>(partial, psums, indptr, NN, nblk);
    scatter_kernel<<<(EE + 255) / 256, 256, 0, stream>>>(ei, indptr, fill, sorted, sdst, EE);
    prep0_kernel<<<3863, 256, 0, stream>>>(w_rest, Bf, att_src, att_dst, w0, bias012, bn_g,
                                           bn_b, bn_m, bn_v, w_edge, att_edge, ea_sums,
                                           wsv, wdv, w0s, w0d, bnss, Mmat, ae_self,
                                           1.0f / EE);
    prep2_kernel<<<235 + nblk, 256, 0, stream>>>(ei, sorted, ea, Mmat, ssrc, aeh_pk,
                                                 x, w0s, w0d, asrcA, adstA, xpad);

    // ---- layer 0 (commuted) ----
    edgep_kernel<<<(EE + 255) / 256, 256, 0, stream>>>(ssrc, sdst, aeh_pk, asrcA, adstA,
                                                       pbuf, 0);
    agg0x_kernel<<<nblk, 256, 0, stream>>>(xpad, asrcA, adstA, ae_self, ssrc,
                                           pbuf, indptr, xagg);
    gemm7f_kernel<<<NN / 32, 256, 0, stream>>>(xagg, w0, bnss, wsv, wdv, h_af, asrcB,
                                               adstB);

    float* asrc_cur = asrcB;
    float* adst_cur = adstB;
    float* asrc_nxt = asrcA;
    float* adst_nxt = adstA;
    for (int i = 1; i < 4; i++) {
        gemmep_kernel<<<EPB + (NP / 128) * (HC / 128), 256, 0, stream>>>(
            h_af, Bf + (size_t)(i - 1) * HC * HC, h_lin,
            ssrc, sdst, aeh_pk, asrc_cur, adst_cur, pbuf, i);
        agg_kernel<<<NN, 256, 0, stream>>>(
            h_lin, asrc_cur, adst_cur, ae_self, ssrc, pbuf, indptr, bnss + (size_t)i * HC,
            wsv + (size_t)i * HC * 4, wdv + (size_t)i * HC * 4, bias3, gate_w, gate_b,
            h_af, asrc_nxt, adst_nxt, h3, gate, i, (i < 3) ? 1 : 0);
        float* tmp = asrc_cur; asrc_cur = asrc_nxt; asrc_nxt = tmp;
        tmp = adst_cur; adst_cur = adst_nxt; adst_nxt = tmp;
    }

    graphagg_kernel<<<BB, 256, 0, stream>>>(gate, h3, bptr, graph);
    proj_kernel<<<256, 256, 0, stream>>>(graph, proj_w, proj_b, out);
}

// Round 15
// 567.059 us; speedup vs baseline: 1.0091x; 1.0091x over previous
//
#include <hip/hip_runtime.h>
#include <math.h>

#define NN 20000
#define NP 20480   // padded to 160*128 (full supertile groups)
#define EE 60000
#define BB 512
#define HC 1024
#define HH 4
#define CC 256

typedef _Float16 f16;
typedef f16 half8 __attribute__((ext_vector_type(8)));
typedef f16 f16x4 __attribute__((ext_vector_type(4)));
typedef float floatx4 __attribute__((ext_vector_type(4)));
typedef float floatx16 __attribute__((ext_vector_type(16)));

// A-fragment (and B-fragment) layout for barrier-free GEMM:
// Af[mblk][iter][kh][rg][kg*32+lr][e] = A[mblk*128 + rg*32 + lr][iter*32 + (kh*2+kg)*8 + e]
__device__ __forceinline__ size_t af_off(int n, int c) {
    int mblk = n >> 7, rr = n & 127;
    int iter = c >> 5, kc = c & 31;
    int kh = kc >> 4, kg = (kc >> 3) & 1, e = kc & 7;
    return ((((size_t)(mblk * 32 + iter) * 2 + kh) * 4 + (rr >> 5)) * 64 +
            (kg * 32 + (rr & 31))) * 8 + e;
}

// XCD-aware node remap (v1, proven R6/R11): blockIdx round-robins the 8 XCDs;
// n = (bid>>3) + (bid&7)*2500 gives XCD k the contiguous node range
// [k*2500,(k+1)*2500): af sub-line chunks of consecutive nodes accumulate in ONE
// XCD's L2 -> full-line HBM writes (WRITE_SIZE 81->40.6MB measured).
// R12 lesson: no nt stores here (defeats write-combining, 4x write amp).
// R14 lesson: producer/consumer XCD alignment is null (L2 doesn't persist
// usefully across kernel boundaries) -- keep the cheap v1 mapping.
__device__ __forceinline__ int node_remap(int bid) {
    return (bid >> 3) + (bid & 7) * 2500;
}

// async global->LDS, 16B per lane (wave-uniform LDS base + lane*16 hardware semantics)
__device__ __forceinline__ void gload16(const f16* g, f16* l) {
    __builtin_amdgcn_global_load_lds((const __attribute__((address_space(1))) void*)g,
                                     (__attribute__((address_space(3))) void*)l, 16, 0, 0);
}

// ---------------- precompute kernels ----------------
// one launch zeroes ea_sums(4f) + counts(NN) + fill(NN) + out(BB*1024f)
__global__ void zero_kernel(float* __restrict__ ea_sums, int* __restrict__ counts,
                            int* __restrict__ fill, float* __restrict__ out) {
    int i = blockIdx.x * 256 + threadIdx.x;
    if (i < 4) ea_sums[i] = 0.f;
    for (int k = i; k < NN; k += 256 * 256) {
        counts[k] = 0;
        fill[k] = 0;
    }
    for (int k = i; k < BB * 1024 / 4; k += 256 * 256) {
        ((float4*)out)[k] = make_float4(0.f, 0.f, 0.f, 0.f);
    }
}

// merged ea_sum + hist [0,235) + bptr [235,314)
__global__ void ehist_kernel(const float* __restrict__ ea, const int* __restrict__ ei,
                             const int* __restrict__ batch, float* sums, int* counts,
                             int* bptr, int E_) {
    int bid = blockIdx.x;
    int t = threadIdx.x;
    if (bid < 235) {
        int e = bid * 256 + t;
        float s0 = 0.f, s1 = 0.f, s2 = 0.f;
        if (e < E_) {
            atomicAdd(&counts[ei[E_ + e]], 1);
            s0 = ea[e * 3 + 0];
            s1 = ea[e * 3 + 1];
            s2 = ea[e * 3 + 2];
        }
        for (int o = 32; o; o >>= 1) {
            s0 += __shfl_down(s0, o);
            s1 += __shfl_down(s1, o);
            s2 += __shfl_down(s2, o);
        }
        if ((t & 63) == 0) {
            atomicAdd(&sums[0], s0);
            atomicAdd(&sums[1], s1);
            atomicAdd(&sums[2], s2);
        }
    } else {
        int i = (bid - 235) * 256 + t;
        if (i >= NN) return;
        int b = batch[i];
        if (i == 0) {
            for (int bb = 0; bb <= b; bb++) bptr[bb] = 0;
        } else {
            int pb = batch[i - 1];
            if (pb != b) {
                for (int bb = pb + 1; bb <= b; bb++) bptr[bb] = i;
            }
        }
        if (i == NN - 1) {
            for (int bb = b + 1; bb <= BB; bb++) bptr[bb] = NN;
        }
    }
}

// scan1: per-block inclusive scan; psums[bid] = raw block total
__global__ void scan1_kernel(const int* __restrict__ counts, int* __restrict__ partial,
                             int* __restrict__ psums, int n) {
    __shared__ int sdata[256];
    int t = threadIdx.x;
    int i = blockIdx.x * 256 + t;
    int v = (i < n) ? counts[i] : 0;
    sdata[t] = v;
    __syncthreads();
#pragma unroll
    for (int off = 1; off < 256; off <<= 1) {
        int tmp = (t >= off) ? sdata[t - off] : 0;
        __syncthreads();
        sdata[t] += tmp;
        __syncthreads();
    }
    if (i < n) partial[i] = sdata[t];
    if (t == 255) psums[blockIdx.x] = sdata[255];
}

// scan3 (scan2 folded in): each block derives its own offset = sum of psums[0..bid)
// via one LDS reduction (nblk = 79 <= 256 threads).
__global__ void scan3_kernel(const int* __restrict__ partial, const int* __restrict__ psums,
                             int* __restrict__ indptr, int n, int nb) {
    __shared__ int soff[256];
    int t = threadIdx.x;
    int v = (t < nb && t < (int)blockIdx.x) ? psums[t] : 0;
    soff[t] = v;
    __syncthreads();
#pragma unroll
    for (int o = 128; o; o >>= 1) {
        if (t < o) soff[t] += soff[t + o];
        __syncthreads();
    }
    int off = soff[0];
    int i = blockIdx.x * 256 + t;
    if (i == 0) indptr[0] = 0;
    if (i < n) indptr[i + 1] = partial[i] + off;
}

__global__ void scatter_kernel(const int* __restrict__ ei, const int* __restrict__ indptr,
                               int* fill, int* sorted, int* sdst, int E_) {
    int e = blockIdx.x * 256 + threadIdx.x;
    if (e >= E_) return;
    int d = ei[E_ + e];
    int pos = indptr[d] + atomicAdd(&fill[d], 1);
    sorted[pos] = e;
    sdst[pos] = d;
}

// merged prep0: wbf [0,768) + wvec/w0vec/bnss [768,3859) + mmat [3859,3863)
__global__ void prep0_kernel(const float* __restrict__ w_rest, f16* __restrict__ Bf,
                             const float* __restrict__ att_src,
                             const float* __restrict__ att_dst,
                             const float* __restrict__ w0,
                             const float* __restrict__ bias012, const float* __restrict__ bn_g,
                             const float* __restrict__ bn_b, const float* __restrict__ bn_m,
                             const float* __restrict__ bn_v,
                             const float* __restrict__ w_edge,
                             const float* __restrict__ att_edge,
                             const float* __restrict__ ea_sums,
                             float* __restrict__ wsv, float* __restrict__ wdv,
                             float* __restrict__ w0s, float* __restrict__ w0d,
                             float2* __restrict__ bnss,
                             float* __restrict__ Mmat, float* __restrict__ ae_self,
                             float invE) {
    int bid = blockIdx.x;
    int t = threadIdx.x;
    if (bid < 768) {
        // wbf: w_rest[3][1024][1024] fp32 -> Bf fragment-major fp16
        __shared__ float tile[64][65];
        int bx = (bid & 15) * 64;        // n range
        int by = ((bid >> 4) & 15) * 64; // k range
        int l = bid >> 8;
        int tr = t >> 6, tc = t & 63;
#pragma unroll
        for (int i = 0; i < 16; i++) {
            int r = by + i * 4 + tr;
            tile[i * 4 + tr][tc] = w_rest[(size_t)l * 1048576 + (size_t)r * 1024 + bx + tc];
        }
        __syncthreads();
        f16* bl = Bf + (size_t)l * 1048576;
#pragma unroll
        for (int ii = 0; ii < 2; ii++) {
            int idx = ii * 256 + t;
            int nl = idx >> 3, kg8 = idx & 7;
            int n = bx + nl, k = by + kg8 * 8;
            half8 v;
#pragma unroll
            for (int e = 0; e < 8; e++) v[e] = (f16)tile[kg8 * 8 + e][nl];
            *(half8*)&bl[af_off(n, k)] = v;
        }
    } else if (bid < 3840) {
        int b = bid - 768;
        int l = b >> 10, k = b & 1023;
        int hp = t >> 6, lane = t & 63;
        int col = hp * 256 + lane * 4;
        const float* wrow = w_rest + (size_t)l * 1048576 + (size_t)k * 1024;
        float4 w4 = *(const float4*)&wrow[col];
        float4 a4 = *(const float4*)&att_src[(l + 1) * HC + col];
        float4 d4 = *(const float4*)&att_dst[(l + 1) * HC + col];
        float sp = w4.x * a4.x + w4.y * a4.y + w4.z * a4.z + w4.w * a4.w;
        float dp = w4.x * d4.x + w4.y * d4.y + w4.z * d4.z + w4.w * d4.w;
        for (int m = 1; m < 64; m <<= 1) {
            sp += __shfl_xor(sp, m);
            dp += __shfl_xor(dp, m);
        }
        if (lane == 0) {
            wsv[((size_t)l * 1024 + k) * 4 + hp] = sp;
            wdv[((size_t)l * 1024 + k) * 4 + hp] = dp;
        }
    } else if (bid < 3847) {
        int f = bid - 3840;
        int hp = t >> 6, lane = t & 63;
        int col = hp * 256 + lane * 4;
        float4 w4 = *(const float4*)&w0[f * HC + col];
        float4 a4 = *(const float4*)&att_src[col];
        float4 d4 = *(const float4*)&att_dst[col];
        float sp = w4.x * a4.x + w4.y * a4.y + w4.z * a4.z + w4.w * a4.w;
        float dp = w4.x * d4.x + w4.y * d4.y + w4.z * d4.z + w4.w * d4.w;
        for (int m = 1; m < 64; m <<= 1) {
            sp += __shfl_xor(sp, m);
            dp += __shfl_xor(dp, m);
        }
        if (lane == 0) {
            w0s[f * 4 + hp] = sp;
            w0d[f * 4 + hp] = dp;
        }
    } else if (bid < 3859) {
        int i = (bid - 3847) * 256 + t;
        if (i < 3 * HC) {
            float s = bn_g[i] * rsqrtf(bn_v[i] + 1e-5f);
            float2 o;
            o.x = s;
            o.y = (bias012[i] - bn_m[i]) * s + bn_b[i];
            bnss[i] = o;
        }
    } else {
        // mmat: Mmat[l][d][h]; ae_self[l][h]
        __shared__ float red[256];
        __shared__ float Ms[12];
        int l = bid - 3859;
        for (int dh = 0; dh < 12; dh++) {
            int d = dh >> 2, hh = dh & 3;
            float v = w_edge[l * 3072 + d * HC + hh * CC + t] *
                      att_edge[l * HC + hh * CC + t];
            red[t] = v;
            __syncthreads();
            for (int o = 128; o; o >>= 1) {
                if (t < o) red[t] += red[t + o];
                __syncthreads();
            }
            if (t == 0) {
                Ms[dh] = red[0];
                Mmat[l * 12 + dh] = red[0];
            }
            __syncthreads();
        }
        if (t < 4) {
            float v = 0.f;
            for (int d = 0; d < 3; d++) v += ea_sums[d] * invE * Ms[d * 4 + t];
            ae_self[l * 4 + t] = v;
        }
    }
}

// merged prep2: pack [0,235) + alpha0/xpad [235,314)
__global__ void prep2_kernel(const int* __restrict__ ei, const int* __restrict__ sorted,
                             const float* __restrict__ ea, const float* __restrict__ Mmat,
                             int* __restrict__ ssrc, float* __restrict__ aeh_pk,
                             const float* __restrict__ x, const float* __restrict__ w0s,
                             const float* __restrict__ w0d, float* __restrict__ asrc,
                             float* __restrict__ adst, float* __restrict__ xpad) {
    int bid = blockIdx.x;
    int t = threadIdx.x;
    if (bid < 235) {
        int idx = bid * 256 + t;
        if (idx >= EE) return;
        int eid = sorted[idx];
        ssrc[idx] = ei[eid];
        float a0 = ea[eid * 3 + 0], a1 = ea[eid * 3 + 1], a2 = ea[eid * 3 + 2];
#pragma unroll
        for (int l = 0; l < 4; l++) {
#pragma unroll
            for (int h = 0; h < 4; h++) {
                aeh_pk[(size_t)idx * 16 + l * 4 + h] =
                    a0 * Mmat[l * 12 + h] + a1 * Mmat[l * 12 + 4 + h] +
                    a2 * Mmat[l * 12 + 8 + h];
            }
        }
    } else {
        int n = (bid - 235) * 256 + t;
        if (n >= NN) return;
        float xr[7];
#pragma unroll
        for (int f = 0; f < 7; f++) xr[f] = x[n * 7 + f];
        float4 p0, p1;
        p0.x = xr[0]; p0.y = xr[1]; p0.z = xr[2]; p0.w = xr[3];
        p1.x = xr[4]; p1.y = xr[5]; p1.z = xr[6]; p1.w = 0.f;
        *(float4*)&xpad[(size_t)n * 8] = p0;
        *(float4*)&xpad[(size_t)n * 8 + 4] = p1;
#pragma unroll
        for (int hp = 0; hp < 4; hp++) {
            float s = 0.f, d = 0.f;
#pragma unroll
            for (int f = 0; f < 7; f++) {
                s += xr[f] * w0s[f * 4 + hp];
                d += xr[f] * w0d[f * 4 + hp];
            }
            asrc[n * 4 + hp] = s;
            adst[n * 4 + hp] = d;
        }
    }
}

// per-layer edge-parallel softmax numerator (standalone for layer 0)
__global__ void edgep_kernel(const int* __restrict__ ssrc, const int* __restrict__ sdst,
                             const float* __restrict__ aeh_pk, const float* __restrict__ asrc,
                             const float* __restrict__ adst, float* __restrict__ pe,
                             int layer) {
    int i = blockIdx.x * 256 + threadIdx.x;
    if (i >= EE) return;
    int src = ssrc[i];
    int dst = sdst[i];
    float4 a = *(const float4*)&asrc[(size_t)src * 4];
    float4 d = *(const float4*)&adst[(size_t)dst * 4];
    float4 m = *(const float4*)&aeh_pk[(size_t)i * 16 + layer * 4];
    float r[4] = {a.x + d.x + m.x, a.y + d.y + m.y, a.z + d.z + m.z, a.w + d.w + m.w};
    float4 o;
#pragma unroll
    for (int k = 0; k < 4; k++) {
        float v = (r[k] > 0.f) ? r[k] : 0.2f * r[k];
        (&o.x)[k] = __expf(v);
    }
    *(float4*)&pe[(size_t)i * 4] = o;
}

// ---------------- layer 0 (commuted) ----------------
__global__ void agg0x_kernel(const float* __restrict__ xpad, const float* __restrict__ asrc,
                             const float* __restrict__ adst, const float* __restrict__ ae_self,
                             const int* __restrict__ ssrc, const float* __restrict__ pe,
                             const int* __restrict__ indptr, float* __restrict__ xagg) {
    int n = blockIdx.x * 256 + threadIdx.x;
    if (n >= NN) return;
    float4 as4 = *(const float4*)&asrc[(size_t)n * 4];
    float4 ad4 = *(const float4*)&adst[(size_t)n * 4];
    float adl[4] = {ad4.x, ad4.y, ad4.z, ad4.w};
    float asl[4] = {as4.x, as4.y, as4.z, as4.w};
    float4 x0 = *(const float4*)&xpad[(size_t)n * 8];
    float4 x1 = *(const float4*)&xpad[(size_t)n * 8 + 4];
    float xr[7] = {x0.x, x0.y, x0.z, x0.w, x1.x, x1.y, x1.z};
    float denom[4];
    float xa[4][7];
#pragma unroll
    for (int h = 0; h < 4; h++) {
        float r = asl[h] + adl[h] + ae_self[h];
        r = (r > 0.f) ? r : 0.2f * r;
        float p = __expf(r);
        denom[h] = p;
#pragma unroll
        for (int f = 0; f < 7; f++) xa[h][f] = p * xr[f];
    }
    int s = indptr[n], e = indptr[n + 1];
    for (int idx = s; idx < e; idx++) {
        int src = ssrc[idx];
        float4 pv = *(const float4*)&pe[(size_t)idx * 4];
        float pl[4] = {pv.x, pv.y, pv.z, pv.w};
        float4 s0 = *(const float4*)&xpad[(size_t)src * 8];
        float4 s1 = *(const float4*)&xpad[(size_t)src * 8 + 4];
        float xs[7] = {s0.x, s0.y, s0.z, s0.w, s1.x, s1.y, s1.z};
#pragma unroll
        for (int h = 0; h < 4; h++) {
            denom[h] += pl[h];
#pragma unroll
            for (int f = 0; f < 7; f++) xa[h][f] += pl[h] * xs[f];
        }
    }
#pragma unroll
    for (int h = 0; h < 4; h++) {
        float inv = 1.0f / (denom[h] + 1e-16f);
#pragma unroll
        for (int f = 0; f < 7; f++) xagg[(size_t)n * 28 + h * 7 + f] = xa[h][f] * inv;
    }
}

// h_act = relu(BN(xagg @ w0)) in Af layout + next-layer alpha epilogue.
// 32 nodes (one lr-group: fixed mblk,rg) per 256-thread block.
__global__ void gemm7f_kernel(const float* __restrict__ xagg, const float* __restrict__ w0,
                              const float2* __restrict__ bnss, const float* __restrict__ wsv,
                              const float* __restrict__ wdv, f16* __restrict__ outAf,
                              float* __restrict__ asrc_n, float* __restrict__ adst_n) {
    __shared__ float xs[32][29];
    __shared__ float red[4][32][8];
    int bid = blockIdx.x;
    int t = threadIdx.x;
    int n0 = bid * 32;
    int mblk = bid >> 2, rg = bid & 3;
    for (int i = t; i < 896; i += 256) xs[i / 28][i % 28] = xagg[(size_t)n0 * 28 + i];
    __syncthreads();
    int w = t >> 6, lane = t & 63;
    int lr = lane & 31, kg = lane >> 5;
    float x7[7];
#pragma unroll
    for (int f = 0; f < 7; f++) x7[f] = xs[lr][w * 7 + f];
    float sp[4] = {0.f, 0.f, 0.f, 0.f}, dp[4] = {0.f, 0.f, 0.f, 0.f};
#pragma unroll
    for (int p = 0; p < 16; p++) {
        int iter = w * 8 + (p >> 1);
        int kh = p & 1;
        int c0 = iter * 32 + (kh * 2 + kg) * 8;
        float dot[8];
#pragma unroll
        for (int e = 0; e < 8; e++) dot[e] = 0.f;
#pragma unroll
        for (int f = 0; f < 7; f++) {
            float4 wa = *(const float4*)&w0[f * HC + c0];
            float4 wb = *(const float4*)&w0[f * HC + c0 + 4];
            dot[0] += x7[f] * wa.x; dot[1] += x7[f] * wa.y;
            dot[2] += x7[f] * wa.z; dot[3] += x7[f] * wa.w;
            dot[4] += x7[f] * wb.x; dot[5] += x7[f] * wb.y;
            dot[6] += x7[f] * wb.z; dot[7] += x7[f] * wb.w;
        }
        half8 o;
#pragma unroll
        for (int e = 0; e < 8; e++) {
            int j = c0 + e;
            float2 ss = bnss[j];
            float val = fmaxf(fmaf(dot[e], ss.x, ss.y), 0.f);
            o[e] = (f16)val;
            float4 w4s = *(const float4*)&wsv[(size_t)j * 4];
            float4 w4d = *(const float4*)&wdv[(size_t)j * 4];
            sp[0] += val * w4s.x; sp[1] += val * w4s.y;
            sp[2] += val * w4s.z; sp[3] += val * w4s.w;
            dp[0] += val * w4d.x; dp[1] += val * w4d.y;
            dp[2] += val * w4d.z; dp[3] += val * w4d.w;
        }
        size_t off = ((((size_t)(mblk * 32 + iter) * 2 + kh) * 4 + rg) * 64 + lane) * 8;
        *(half8*)&outAf[off] = o;
    }
#pragma unroll
    for (int q = 0; q < 4; q++) {
        sp[q] += __shfl_xor(sp[q], 32);
        dp[q] += __shfl_xor(dp[q], 32);
    }
    if (kg == 0) {
#pragma unroll
        for (int q = 0; q < 4; q++) {
            red[w][lr][q] = sp[q];
            red[w][lr][4 + q] = dp[q];
        }
    }
    __syncthreads();
    {
        int lr2 = t >> 3, q = t & 7;
        float v = red[0][lr2][q] + red[1][lr2][q] + red[2][lr2][q] + red[3][lr2][q];
        if (q < 4) asrc_n[(size_t)(n0 + lr2) * 4 + q] = v;
        else adst_n[(size_t)(n0 + lr2) * 4 + (q - 4)] = v;
    }
}

// ---------------- GEMM (layers 1-3) + fused edgep ----------------
// Blocks [0,235): edgep. Blocks [235,1515): LDS GEMM, 3-buffer rotation (BK=32,
// 3 x 16KB = 48KB LDS -> 3 blocks/CU): ONE barrier per K-tile; counted vmcnt(4)
// keeps the next tile's loads in flight across the barrier (T4); stage before
// MFMA cluster (T3); setprio around MFMA (T5); sched_barrier fences (rule #18).
#define EPB 235
__global__ __launch_bounds__(256) void gemmep_kernel(
    const f16* __restrict__ Af, const f16* __restrict__ Bf, f16* __restrict__ C16,
    const int* __restrict__ ssrc, const int* __restrict__ sdst,
    const float* __restrict__ aeh_pk, const float* __restrict__ asrc,
    const float* __restrict__ adst, float* __restrict__ pe, int layer) {
    __shared__ __align__(16) f16 lds[24576];  // 3 bufs x (4096 A + 4096 B) f16
    int t = threadIdx.x;
    int bid = blockIdx.x;
    if (bid < EPB) {
        int i = bid * 256 + t;
        if (i >= EE) return;
        int src = ssrc[i];
        int dst = sdst[i];
        float4 a = *(const float4*)&asrc[(size_t)src * 4];
        float4 d = *(const float4*)&adst[(size_t)dst * 4];
        float4 m = *(const float4*)&aeh_pk[(size_t)i * 16 + layer * 4];
        float r[4] = {a.x + d.x + m.x, a.y + d.y + m.y, a.z + d.z + m.z, a.w + d.w + m.w};
        float4 o;
#pragma unroll
        for (int k = 0; k < 4; k++) {
            float v = (r[k] > 0.f) ? r[k] : 0.2f * r[k];
            (&o.x)[k] = __expf(v);
        }
        *(float4*)&pe[(size_t)i * 4] = o;
        return;
    }
    int gid = bid - EPB;
    int w = t >> 6, lane = t & 63;
    int g = gid >> 6, rblk = gid & 63;
    int nblk = rblk >> 3;
    int mblk = g * 8 + (rblk & 7);
    int rg0 = (w >> 1) * 2;
    int cg0 = (w & 1) * 2;

    floatx16 acc[2][2];
#pragma unroll
    for (int i = 0; i < 2; i++)
#pragma unroll
        for (int j = 0; j < 2; j++) acc[i][j] = (floatx16)(0.f);

    const f16* ga0 = Af + (size_t)mblk * 131072 + w * 1024 + lane * 8;
    const f16* gb0 = Bf + (size_t)nblk * 131072 + w * 1024 + lane * 8;

    // stage iter 'it' into buffer b: 4 async 1KB-per-wave issues
    auto STAGE = [&](int it, int b) {
        const f16* ga = ga0 + (size_t)it * 4096;
        const f16* gb = gb0 + (size_t)it * 4096;
        f16* base = &lds[b * 8192 + w * 1024 + lane * 8];
        gload16(ga, base);
        gload16(ga + 512, base + 512);
        gload16(gb, base + 4096);
        gload16(gb + 512, base + 4608);
    };
    auto COMPUTE = [&](int b) {
        half8 afr[2][2], bfr[2][2];
#pragma unroll
        for (int kh = 0; kh < 2; kh++) {
#pragma unroll
            for (int i = 0; i < 2; i++) {
                afr[kh][i] = *(const half8*)&lds[b * 8192 + kh * 2048 + (rg0 + i) * 512 +
                                                 lane * 8];
                bfr[kh][i] = *(const half8*)&lds[b * 8192 + 4096 + kh * 2048 +
                                                 (cg0 + i) * 512 + lane * 8];
            }
        }
#pragma unroll
        for (int kh = 0; kh < 2; kh++)
#pragma unroll
            for (int i = 0; i < 2; i++)
#pragma unroll
                for (int j = 0; j < 2; j++)
                    acc[i][j] = __builtin_amdgcn_mfma_f32_32x32x16_f16(bfr[kh][j], afr[kh][i],
                                                                       acc[i][j], 0, 0, 0);
    };

    STAGE(0, 0);
    STAGE(1, 1);
    int cb = 0, sb = 2;
#pragma unroll 1
    for (int k = 0; k < 31; k++) {
        asm volatile("s_waitcnt vmcnt(4)" ::: "memory");
        __builtin_amdgcn_s_barrier();
        __builtin_amdgcn_sched_barrier(0);
        if (k < 30) {
            STAGE(k + 2, sb);
            sb = (sb == 2) ? 0 : sb + 1;
        }
        __builtin_amdgcn_s_setprio(1);
        COMPUTE(cb);
        __builtin_amdgcn_s_setprio(0);
        cb = (cb == 2) ? 0 : cb + 1;
    }
    asm volatile("s_waitcnt vmcnt(0)" ::: "memory");
    __builtin_amdgcn_s_barrier();
    __builtin_amdgcn_sched_barrier(0);
    __builtin_amdgcn_s_setprio(1);
    COMPUTE(cb);
    __builtin_amdgcn_s_setprio(0);

    int fr32 = lane & 31, kg = lane >> 5;
#pragma unroll
    for (int i = 0; i < 2; i++) {
        int row = mblk * 128 + rg0 * 32 + i * 32 + fr32;
#pragma unroll
        for (int j = 0; j < 2; j++) {
#pragma unroll
            for (int gq = 0; gq < 4; gq++) {
                f16x4 o;
#pragma unroll
                for (int r = 0; r < 4; r++) o[r] = (f16)acc[i][j][gq * 4 + r];
                *(f16x4*)&C16[(size_t)row * HC + nblk * 128 + cg0 * 32 + j * 32 + gq * 8 +
                              kg * 4] = o;
            }
        }
    }
}

// ---------------- fused attention + aggregation (block per node, chunk-4) ----------
// R8-proven inner loop (unconditional gathers + self-row fallback).
__global__ void agg_kernel(const f16* __restrict__ h16, const float* __restrict__ asrc,
                           const float* __restrict__ adst, const float* __restrict__ ae_self,
                           const int* __restrict__ ssrc, const float* __restrict__ pe,
                           const int* __restrict__ indptr, const float2* __restrict__ bnss,
                           const float* __restrict__ wsv, const float* __restrict__ wdv,
                           const float* __restrict__ bias3, const float* __restrict__ gw,
                           const float* __restrict__ gb, f16* __restrict__ out16,
                           float* __restrict__ asrc_n, float* __restrict__ adst_n,
                           float* __restrict__ out3, float* __restrict__ gate,
                           int layer, int concat) {
    __shared__ float buf[1024];
    __shared__ float red[32];
    int n = node_remap(blockIdx.x);
    int t = threadIdx.x;
    int h = t >> 6, lane = t & 63;
    int c4 = t * 4;

    float r = asrc[n * 4 + h] + adst[n * 4 + h] + ae_self[layer * 4 + h];
    r = (r > 0.f) ? r : 0.2f * r;
    float p = __expf(r);
    float denom = p;
    float ax, ay, az, aw;
    {
        f16x4 v = *(const f16x4*)&h16[(size_t)n * HC + c4];
        ax = p * (float)v[0]; ay = p * (float)v[1];
        az = p * (float)v[2]; aw = p * (float)v[3];
    }
    int s = indptr[n], epos = indptr[n + 1];
    for (int base = s; base < epos; base += 4) {
        int rem = epos - base;
        int src[4];
        float pv[4];
#pragma unroll
        for (int j = 0; j < 4; j++) {
            if (j < rem) {
                src[j] = ssrc[base + j];
                pv[j] = pe[(size_t)(base + j) * 4 + h];
            } else {
                src[j] = n;
                pv[j] = 0.f;
            }
        }
        f16x4 u[4];
#pragma unroll
        for (int j = 0; j < 4; j++) u[j] = *(const f16x4*)&h16[(size_t)src[j] * HC + c4];
#pragma unroll
        for (int j = 0; j < 4; j++) {
            denom += pv[j];
            ax += pv[j] * (float)u[j][0];
            ay += pv[j] * (float)u[j][1];
            az += pv[j] * (float)u[j][2];
            aw += pv[j] * (float)u[j][3];
        }
    }
    float inv = 1.0f / (denom + 1e-16f);
    ax *= inv; ay *= inv; az *= inv; aw *= inv;

    if (concat) {
        float vals[4] = {ax, ay, az, aw};
        f16x4 o;
        float sp[4] = {0.f, 0.f, 0.f, 0.f}, dp[4] = {0.f, 0.f, 0.f, 0.f};
#pragma unroll
        for (int k = 0; k < 4; k++) {
            int j = c4 + k;
            float2 ss = bnss[j];
            float val = fmaxf(fmaf(vals[k], ss.x, ss.y), 0.f);
            o[k] = (f16)val;
            float4 w4s = *(const float4*)&wsv[(size_t)j * 4];
            float4 w4d = *(const float4*)&wdv[(size_t)j * 4];
            sp[0] += val * w4s.x; sp[1] += val * w4s.y;
            sp[2] += val * w4s.z; sp[3] += val * w4s.w;
            dp[0] += val * w4d.x; dp[1] += val * w4d.y;
            dp[2] += val * w4d.z; dp[3] += val * w4d.w;
        }
        *(f16x4*)&out16[af_off(n, c4)] = o;
#pragma unroll
        for (int m = 1; m < 64; m <<= 1) {
#pragma unroll
            for (int j = 0; j < 4; j++) {
                sp[j] += __shfl_xor(sp[j], m);
                dp[j] += __shfl_xor(dp[j], m);
            }
        }
        if (lane == 0) {
#pragma unroll
            for (int j = 0; j < 4; j++) {
                red[h * 8 + j] = sp[j];
                red[h * 8 + 4 + j] = dp[j];
            }
        }
        __syncthreads();
        if (t < 8) {
            float v = red[t] + red[8 + t] + red[16 + t] + red[24 + t];
            if (t < 4) asrc_n[n * 4 + t] = v;
            else adst_n[n * 4 + (t - 4)] = v;
        }
    } else {
        buf[c4 + 0] = ax;
        buf[c4 + 1] = ay;
        buf[c4 + 2] = az;
        buf[c4 + 3] = aw;
        __syncthreads();
        if (t < 64) {
            float gpart = 0.f;
            float4 v4;
#pragma unroll
            for (int k = 0; k < 4; k++) {
                int c = t * 4 + k;
                float v2 = 0.25f * (buf[c] + buf[256 + c] + buf[512 + c] + buf[768 + c]) +
                           bias3[c];
                (&v4.x)[k] = v2;
                gpart += v2 * gw[c];
            }
            *(float4*)&out3[(size_t)n * CC + t * 4] = v4;
            for (int o = 32; o; o >>= 1) gpart += __shfl_down(gpart, o);
            if (t == 0) gate[n] = gpart + gb[0];
        }
    }
}

// ---------------- readout ----------------
__global__ void graphagg_kernel(const float* __restrict__ gate, const float* __restrict__ h3,
                                const int* __restrict__ bptr, float* __restrict__ graph) {
    __shared__ float red[256];
    __shared__ float wn[256];
    int b = blockIdx.x, t = threadIdx.x;
    int s = bptr[b], epos = bptr[b + 1];
    float m = -3.4e38f;
    for (int n = s + t; n < epos; n += 256) m = fmaxf(m, gate[n]);
    red[t] = m;
    __syncthreads();
    for (int o = 128; o; o >>= 1) {
        if (t < o) red[t] = fmaxf(red[t], red[t + o]);
        __syncthreads();
    }
    float mval = red[0];
    __syncthreads();
    float sum = 0.f;
    for (int n = s + t; n < epos; n += 256) sum += __expf(gate[n] - mval);
    red[t] = sum;
    __syncthreads();
    for (int o = 128; o; o >>= 1) {
        if (t < o) red[t] += red[t + o];
        __syncthreads();
    }
    float ssum = red[0];
    __syncthreads();
    float acc = 0.f;
    for (int base = s; base < epos; base += 256) {
        int n = base + t;
        wn[t] = (n < epos) ? __expf(gate[n] - mval) : 0.f;
        __syncthreads();
        int cnt = min(256, epos - base);
        for (int j = 0; j < cnt; j++) acc += wn[j] * h3[(size_t)(base + j) * CC + t];
        __syncthreads();
    }
    graph[b * CC + t] = acc / (ssum + 1e-16f);
}

// 4-way c-split x 64 graph-groups = 256 blocks; out pre-zeroed, partials atomicAdd
// (disjoint cache lines, no contention). Chunk 0 adds the bias.
__global__ void proj_kernel(const float* __restrict__ graph, const float* __restrict__ pw,
                            const float* __restrict__ pb, float* __restrict__ out) {
    __shared__ float g[8][64];
    int bid = blockIdx.x;
    int grp = bid >> 2, cch = bid & 3;
    int t = threadIdx.x;
    int c0 = cch * 64;
    for (int i = t; i < 512; i += 256) {
        int r = i >> 6, c = i & 63;
        g[r][c] = graph[(size_t)(grp * 8 + r) * 256 + c0 + c];
    }
    __syncthreads();
    float acc[8][4];
#pragma unroll
    for (int r = 0; r < 8; r++)
#pragma unroll
        for (int q = 0; q < 4; q++) acc[r][q] = 0.f;
    if (cch == 0) {
#pragma unroll
        for (int q = 0; q < 4; q++) {
            float b = pb[t + q * 256];
#pragma unroll
            for (int r = 0; r < 8; r++) acc[r][q] += b;
        }
    }
    for (int c = 0; c < 64; c++) {
        float w[4];
#pragma unroll
        for (int q = 0; q < 4; q++) w[q] = pw[(size_t)(c0 + c) * 1024 + t + q * 256];
#pragma unroll
        for (int r = 0; r < 8; r++) {
            float gv = g[r][c];
#pragma unroll
            for (int q = 0; q < 4; q++) acc[r][q] += gv * w[q];
        }
    }
#pragma unroll
    for (int r = 0; r < 8; r++)
#pragma unroll
        for (int q = 0; q < 4; q++)
            atomicAdd(&out[(size_t)(grp * 8 + r) * 1024 + t + q * 256], acc[r][q]);
}

// ---------------- host ----------------
extern "C" void kernel_launch(void* const* d_in, const int* in_sizes, int n_in,
                              void* d_out, int out_size, void* d_ws, size_t ws_size,
                              hipStream_t stream) {
    const float* x = (const float*)d_in[0];
    const int* ei = (const int*)d_in[1];
    const float* ea = (const float*)d_in[2];
    const int* batch = (const int*)d_in[3];
    const float* w0 = (const float*)d_in[4];
    const float* w_rest = (const float*)d_in[5];
    const float* w_edge = (const float*)d_in[6];
    const float* att_src = (const float*)d_in[7];
    const float* att_dst = (const float*)d_in[8];
    const float* att_edge = (const float*)d_in[9];
    const float* bias012 = (const float*)d_in[10];
    const float* bias3 = (const float*)d_in[11];
    const float* bn_g = (const float*)d_in[12];
    const float* bn_b = (const float*)d_in[13];
    const float* bn_m = (const float*)d_in[14];
    const float* bn_v = (const float*)d_in[15];
    const float* gate_w = (const float*)d_in[16];
    const float* gate_b = (const float*)d_in[17];
    const float* proj_w = (const float*)d_in[18];
    const float* proj_b = (const float*)d_in[19];
    float* out = (float*)d_out;

    float* ws = (float*)d_ws;
    size_t off = 0;
    f16* h_lin = (f16*)(ws + off); off += (size_t)NP * HC / 2;   // GEMM output (row-major)
    f16* h_af = (f16*)(ws + off); off += (size_t)NP * HC / 2;    // GEMM input (Af layout)
    float* h3 = ws + off; off += (size_t)NN * CC;
    f16* Bf = (f16*)(ws + off); off += (size_t)3 * HC * HC / 2;  // B fragment-major
    float* xpad = ws + off; off += (size_t)NN * 8;
    float* asrcA = ws + off; off += (size_t)NN * 4;
    float* adstA = ws + off; off += (size_t)NN * 4;
    float* asrcB = ws + off; off += (size_t)NN * 4;
    float* adstB = ws + off; off += (size_t)NN * 4;
    float* wsv = ws + off; off += (size_t)3 * HC * 4;
    float* wdv = ws + off; off += (size_t)3 * HC * 4;
    float* w0s = ws + off; off += 28;
    float* w0d = ws + off; off += 28;
    float2* bnss = (float2*)(ws + off); off += (size_t)3 * HC * 2;
    float* aeh_pk = ws + off; off += (size_t)EE * 16;
    float* pbuf = ws + off; off += (size_t)EE * 4;
    float* xagg = ws + off; off += (size_t)NN * 28;
    float* gate = ws + off; off += (size_t)NN;
    float* graph = ws + off; off += (size_t)BB * CC;
    float* ea_sums = ws + off; off += 4;
    float* Mmat = ws + off; off += 48;
    float* ae_self = ws + off; off += 16;
    int* counts = (int*)(ws + off); off += NN;
    int* partial = (int*)(ws + off); off += NN;
    int* psums = (int*)(ws + off); off += 128;
    int* indptr = (int*)(ws + off); off += NN + 1;
    int* fill = (int*)(ws + off); off += NN;
    int* sorted = (int*)(ws + off); off += EE;
    int* ssrc = (int*)(ws + off); off += EE;
    int* sdst = (int*)(ws + off); off += EE;
    int* bptr = (int*)(ws + off); off += BB + 1;

    int nblk = (NN + 255) / 256;  // 79
    zero_kernel<<<256, 256, 0, stream>>>(ea_sums, counts, fill, out);
    ehist_kernel<<<235 + nblk, 256, 0, stream>>>(ea, ei, batch, ea_sums, counts, bptr, EE);
    scan1_kernel<<<nblk, 256, 0, stream>>>(counts, partial, psums, NN);
    scan3_kernel<<<nblk, 256, 0, stream>>>(partial, psums, indptr, NN, nblk);
    scatter_kernel<<<(EE + 255) / 256, 256, 0, stream>>>(ei, indptr, fill, sorted, sdst, EE);
    prep0_kernel<<<3863, 256, 0, stream>>>(w_rest, Bf, att_src, att_dst, w0, bias012, bn_g,
                                           bn_b, bn_m, bn_v, w_edge, att_edge, ea_sums,
                                           wsv, wdv, w0s, w0d, bnss, Mmat, ae_self,
                                           1.0f / EE);
    prep2_kernel<<<235 + nblk, 256, 0, stream>>>(ei, sorted, ea, Mmat, ssrc, aeh_pk,
                                                 x, w0s, w0d, asrcA, adstA, xpad);

    // ---- layer 0 (commuted) ----
    edgep_kernel<<<(EE + 255) / 256, 256, 0, stream>>>(ssrc, sdst, aeh_pk, asrcA, adstA,
                                                       pbuf, 0);
    agg0x_kernel<<<nblk, 256, 0, stream>>>(xpad, asrcA, adstA, ae_self, ssrc,
                                           pbuf, indptr, xagg);
    gemm7f_kernel<<<NN / 32, 256, 0, stream>>>(xagg, w0, bnss, wsv, wdv, h_af, asrcB,
                                               adstB);

    float* asrc_cur = asrcB;
    float* adst_cur = adstB;
    float* asrc_nxt = asrcA;
    float* adst_nxt = adstA;
    for (int i = 1; i < 4; i++) {
        gemmep_kernel<<<EPB + (NP / 128) * (HC / 128), 256, 0, stream>>>(
            h_af, Bf + (size_t)(i - 1) * HC * HC, h_lin,
            ssrc, sdst, aeh_pk, asrc_cur, adst_cur, pbuf, i);
        agg_kernel<<<NN, 256, 0, stream>>>(
            h_lin, asrc_cur, adst_cur, ae_self, ssrc, pbuf, indptr, bnss + (size_t)i * HC,
            wsv + (size_t)i * HC * 4, wdv + (size_t)i * HC * 4, bias3, gate_w, gate_b,
            h_af, asrc_nxt, adst_nxt, h3, gate, i, (i < 3) ? 1 : 0);
        float* tmp = asrc_cur; asrc_cur = asrc_nxt; asrc_nxt = tmp;
        tmp = adst_cur; adst_cur = adst_nxt; adst_nxt = tmp;
    }

    graphagg_kernel<<<BB, 256, 0, stream>>>(gate, h3, bptr, graph);
    proj_kernel<<<256, 256, 0, stream>>>(graph, proj_w, proj_b, out);
}